// Round 5
// baseline (2044.967 us; speedup 1.0000x reference)
//
#include <hip/hip_runtime.h>

#define NODES   30000
#define E0N     480000
#define ETOT    510000   // E0N + NODES self loops
#define D0      100
#define WDIM    300      // H*F = 3*100
#define NW      600      // dual output width
#define NEG     0.2f
#define HSLOT   112      // padded per-head slot count (16-aligned)
#define SLOTS   336      // 3*HSLOT
#define NJ      21       // slots per lane at 16 lanes (336/16)

typedef __bf16 bf16x8 __attribute__((ext_vector_type(8)));
typedef float  f32x4  __attribute__((ext_vector_type(4)));

// ---------------- embedding gather: h[i,k] = emb[x[i],k] ----------------
__global__ void gather_emb(const int* __restrict__ x, const float* __restrict__ emb,
                           float* __restrict__ h, int n, int d) {
    int t = blockIdx.x * 256 + threadIdx.x;
    if (t >= n * d) return;
    int i = t / d, k = t - i * d;
    h[t] = emb[x[i] * d + k];
}

// ---------------- CSR build ----------------
__global__ void count_edges(const int* __restrict__ ei, int* __restrict__ counts) {
    int e = blockIdx.x * 256 + threadIdx.x;
    if (e >= ETOT) return;
    int d = (e < E0N) ? ei[E0N + e] : (e - E0N);
    atomicAdd(&counts[d], 1);
}

__global__ __launch_bounds__(1024) void scan_kernel(const int* __restrict__ counts,
                                                    int* __restrict__ offsets, int n) {
    __shared__ int lds[1024];
    const int CH = 32;
    int t = threadIdx.x;
    int base = t * CH;
    int loc[CH];
    int sum = 0;
    #pragma unroll
    for (int i = 0; i < CH; i++) {
        int v = (base + i < n) ? counts[base + i] : 0;
        loc[i] = sum;
        sum += v;
    }
    lds[t] = sum;
    __syncthreads();
    for (int off = 1; off < 1024; off <<= 1) {
        int v = (t >= off) ? lds[t - off] : 0;
        __syncthreads();
        lds[t] += v;
        __syncthreads();
    }
    int ex = (t == 0) ? 0 : lds[t - 1];
    #pragma unroll
    for (int i = 0; i < CH; i++) {
        int idx = base + i;
        if (idx < n) offsets[idx] = ex + loc[i];
    }
    if (t == 0) offsets[n] = lds[1023];
}

__global__ void scatter_edges(const int* __restrict__ ei, const int* __restrict__ offsets,
                              int* __restrict__ cursor, int* __restrict__ csr_src) {
    int e = blockIdx.x * 256 + threadIdx.x;
    if (e >= ETOT) return;
    int s, d;
    if (e < E0N) { s = ei[e]; d = ei[E0N + e]; }
    else         { s = e - E0N; d = s; }
    int pos = offsets[d] + atomicAdd(&cursor[d], 1);
    csr_src[pos] = s;
}

// ---------------- B fragment pre-split (hi/lo bf16, MFMA-fragment-linear) ----
__global__ void make_bfrag(const float* __restrict__ Bl, const float* __restrict__ Br,
                           bf16x8* __restrict__ out, int K, int ksteps) {
    int t = blockIdx.x * 256 + threadIdx.x;
    int total = ksteps * 40 * 64;
    if (t >= total) return;
    int lane = t & 63;
    int n16  = (t >> 6) % 40;
    int s    = t / (64 * 40);
    int c = n16 * 16 + (lane & 15);
    union { bf16x8 v; __bf16 e[8]; } hi, lo;
    #pragma unroll
    for (int j = 0; j < 8; j++) {
        int k = s * 32 + ((lane >> 4) * 8) + j;
        float x = 0.f;
        if (k < K && c < NW)
            x = (c < WDIM) ? Bl[(size_t)k * WDIM + c] : Br[(size_t)k * WDIM + c - WDIM];
        __bf16 h = (__bf16)x;
        hi.e[j] = h;
        lo.e[j] = (__bf16)(x - (float)h);
    }
    size_t base = ((size_t)(s * 40 + n16) * 2) * 64 + lane;
    out[base]      = hi.v;
    out[base + 64] = lo.v;
}

// ---------------- MFMA dual GEMM -> head-major padded output [N][3][112] ----
__global__ __launch_bounds__(256) void gemm_mfma(
    const float* __restrict__ A, const bf16x8* __restrict__ Bfrag,
    const float* __restrict__ bl, const float* __restrict__ br,
    float* __restrict__ Cl, float* __restrict__ Cr,
    int M, int K, int ksteps) {

    __shared__ bf16x8 Alds[8][2][64];   // [m16][part][slot]
    __shared__ bf16x8 Blds[8][2][64];   // [n16][part][slot]

    int id = blockIdx.x;
    int mb = (id & 7) + 8 * (id / 40);
    int cb = (id >> 3) % 5;
    if (mb >= 235) return;

    int tid  = threadIdx.x;
    int lane = tid & 63;
    int wid  = tid >> 6;
    int wm = wid >> 1, wn = wid & 1;
    int row0 = mb * 128;

    f32x4 acc[4][4] = {};

    for (int s = 0; s < ksteps; s++) {
        int kt = s * 32;
        #pragma unroll
        for (int u0 = 0; u0 < 2; u0++) {
            int u = u0 * 256 + tid;
            int m16  = u >> 6;
            int slot = u & 63;
            int kh = slot >> 4, rl = slot & 15;
            int gr = row0 + m16 * 16 + rl;
            int gc = kt + kh * 8;
            float4 v0 = make_float4(0.f,0.f,0.f,0.f), v1 = v0;
            if (gr < M) {
                const float* ap = A + (size_t)gr * K + gc;
                if (gc + 4 <= K) v0 = *(const float4*)ap;
                if (gc + 8 <= K) v1 = *(const float4*)(ap + 4);
            }
            union { bf16x8 v; __bf16 e[8]; } hi, lo;
            const float* xs0 = (const float*)&v0;
            const float* xs1 = (const float*)&v1;
            #pragma unroll
            for (int j = 0; j < 8; j++) {
                float x = (j < 4) ? xs0[j] : xs1[j - 4];
                __bf16 h = (__bf16)x;
                hi.e[j] = h;
                lo.e[j] = (__bf16)(x - (float)h);
            }
            Alds[m16][0][slot] = hi.v;
            Alds[m16][1][slot] = lo.v;
        }
        {
            const float4* bsrc = (const float4*)(Bfrag + ((size_t)(s * 40 + cb * 8) * 2) * 64);
            float4* bdst = (float4*)&Blds[0][0][0];
            #pragma unroll
            for (int c = 0; c < 4; c++)
                bdst[c * 256 + tid] = bsrc[c * 256 + tid];
        }
        __syncthreads();

        bf16x8 af[4][2], bfr[4][2];
        #pragma unroll
        for (int m = 0; m < 4; m++) {
            af[m][0] = Alds[wm * 4 + m][0][lane];
            af[m][1] = Alds[wm * 4 + m][1][lane];
        }
        #pragma unroll
        for (int n = 0; n < 4; n++) {
            bfr[n][0] = Blds[wn * 4 + n][0][lane];
            bfr[n][1] = Blds[wn * 4 + n][1][lane];
        }
        #pragma unroll
        for (int m = 0; m < 4; m++)
            #pragma unroll
            for (int n = 0; n < 4; n++) {
                acc[m][n] = __builtin_amdgcn_mfma_f32_16x16x32_bf16(af[m][1], bfr[n][1], acc[m][n], 0, 0, 0);
                acc[m][n] = __builtin_amdgcn_mfma_f32_16x16x32_bf16(af[m][1], bfr[n][0], acc[m][n], 0, 0, 0);
                acc[m][n] = __builtin_amdgcn_mfma_f32_16x16x32_bf16(af[m][0], bfr[n][1], acc[m][n], 0, 0, 0);
                acc[m][n] = __builtin_amdgcn_mfma_f32_16x16x32_bf16(af[m][0], bfr[n][0], acc[m][n], 0, 0, 0);
            }
        __syncthreads();
    }

    // epilogue: D row=(lane>>4)*4+reg, col=lane&15; bias; padded-head store
    int r0 = row0 + wm * 64;
    int c0 = cb * 128 + wn * 64;
    #pragma unroll
    for (int m = 0; m < 4; m++)
        #pragma unroll
        for (int n = 0; n < 4; n++) {
            #pragma unroll
            for (int reg = 0; reg < 4; reg++) {
                int gr = r0 + m * 16 + (lane >> 4) * 4 + reg;
                int gc = c0 + n * 16 + (lane & 15);
                if (gr < M && gc < NW) {
                    bool left = gc < WDIM;
                    int cc = left ? gc : gc - WDIM;
                    int head = cc / 100;
                    int fh = cc - head * 100;
                    float v = acc[m][n][reg] + (left ? bl[cc] : br[cc]);
                    (left ? Cl : Cr)[(size_t)gr * SLOTS + head * HSLOT + fh] = v;
                }
            }
        }
}

// ---------------- fused GAT: 4 edges/wave, 16 lanes/edge, online softmax ----
__global__ __launch_bounds__(256) void gat_edge_agg(
    const float* __restrict__ xlp, const float* __restrict__ xrp,
    const int* __restrict__ offsets, const int* __restrict__ csr_src,
    const float* __restrict__ att, const float* __restrict__ bias,
    float* __restrict__ hout) {
    int node = (blockIdx.x * 256 + threadIdx.x) >> 6;
    int lane = threadIdx.x & 63;
    if (node >= NODES) return;
    int ql = lane & 15;
    int g  = lane >> 4;

    // per-lane resident: att weights (0 at pads) and xr row (garbage at pads, killed by aw=0)
    float aw[NJ], xrv[NJ];
    #pragma unroll
    for (int j = 0; j < NJ; j++) {
        int head = j / 7, fh = ql + 16 * (j % 7);
        aw[j]  = (fh < 100) ? att[head * 100 + fh] : 0.f;
        xrv[j] = xrp[(size_t)node * SLOTS + head * HSLOT + fh];
    }

    float m0 = -1e38f, m1 = -1e38f, m2 = -1e38f;
    float s0 = 0.f, s1 = 0.f, s2 = 0.f;
    float acc[NJ] = {};

    int beg = offsets[node], end = offsets[node + 1];
    int nit = (end - beg + 3) >> 2;
    for (int it = 0; it < nit; it++) {
        int i = beg + it * 4 + g;
        bool active = i < end;
        int sid = csr_src[active ? i : end - 1];
        const float* row = xlp + (size_t)sid * SLOTS + ql;
        float v[NJ];
        float p0 = 0.f, p1 = 0.f, p2 = 0.f;
        #pragma unroll
        for (int j = 0; j < NJ; j++) {
            v[j] = row[(j / 7) * HSLOT + 16 * (j % 7)];
            float t = v[j] + xrv[j];
            t = fmaxf(t, NEG * t);          // leaky-relu (NEG>0)
            float pv = t * aw[j];
            if (j < 7) p0 += pv; else if (j < 14) p1 += pv; else p2 += pv;
        }
        // packed 16-lane reduce of (p0,p1,p2)
        p0 += __shfl_xor(p0, 1, 64); p1 += __shfl_xor(p1, 1, 64); p2 += __shfl_xor(p2, 1, 64);
        p0 += __shfl_xor(p0, 2, 64); p1 += __shfl_xor(p1, 2, 64); p2 += __shfl_xor(p2, 2, 64);
        int r = lane & 3;
        float q = (r == 1) ? p1 : ((r == 2) ? p2 : p0);
        q += __shfl_xor(q, 4, 64);
        q += __shfl_xor(q, 8, 64);
        int gb = lane & 48;
        p0 = __shfl(q, gb, 64);
        p1 = __shfl(q, gb + 1, 64);
        p2 = __shfl(q, gb + 2, 64);
        if (!active) { p0 = -3e38f; p1 = -3e38f; p2 = -3e38f; }

        // defer-rescale online softmax (THR=8)
        if (p0 > m0 + 8.f || p1 > m1 + 8.f || p2 > m2 + 8.f) {
            float nm0 = fmaxf(m0, p0), nm1 = fmaxf(m1, p1), nm2 = fmaxf(m2, p2);
            float e0 = __expf(m0 - nm0), e1 = __expf(m1 - nm1), e2 = __expf(m2 - nm2);
            s0 *= e0; s1 *= e1; s2 *= e2;
            #pragma unroll
            for (int j = 0; j < NJ; j++)
                acc[j] *= (j < 7) ? e0 : ((j < 14) ? e1 : e2);
            m0 = nm0; m1 = nm1; m2 = nm2;
        }
        float c0 = __expf(p0 - m0), c1 = __expf(p1 - m1), c2 = __expf(p2 - m2);
        s0 += c0; s1 += c1; s2 += c2;
        #pragma unroll
        for (int j = 0; j < NJ; j++)
            acc[j] = fmaf((j < 7) ? c0 : ((j < 14) ? c1 : c2), v[j], acc[j]);
    }

    // exact cross-group merge (groups at lane^16, lane^32)
    float M0 = fmaxf(m0, __shfl_xor(m0, 16, 64)); M0 = fmaxf(M0, __shfl_xor(M0, 32, 64));
    float M1 = fmaxf(m1, __shfl_xor(m1, 16, 64)); M1 = fmaxf(M1, __shfl_xor(M1, 32, 64));
    float M2 = fmaxf(m2, __shfl_xor(m2, 16, 64)); M2 = fmaxf(M2, __shfl_xor(M2, 32, 64));
    float sc0 = __expf(m0 - M0), sc1 = __expf(m1 - M1), sc2 = __expf(m2 - M2);
    s0 *= sc0; s0 += __shfl_xor(s0, 16, 64); s0 += __shfl_xor(s0, 32, 64);
    s1 *= sc1; s1 += __shfl_xor(s1, 16, 64); s1 += __shfl_xor(s1, 32, 64);
    s2 *= sc2; s2 += __shfl_xor(s2, 16, 64); s2 += __shfl_xor(s2, 32, 64);
    #pragma unroll
    for (int j = 0; j < NJ; j++) {
        float a = acc[j] * ((j < 7) ? sc0 : ((j < 14) ? sc1 : sc2));
        a += __shfl_xor(a, 16, 64);
        a += __shfl_xor(a, 32, 64);
        acc[j] = a;
    }
    float i0 = 1.f / s0, i1 = 1.f / s1, i2 = 1.f / s2;
    if (lane < 16) {
        #pragma unroll
        for (int j = 0; j < NJ; j++) {
            int head = j / 7, fh = ql + 16 * (j % 7);
            if (fh < 100) {
                int f = head * 100 + fh;
                float o = acc[j] * ((j < 7) ? i0 : ((j < 14) ? i1 : i2)) + bias[f];
                hout[(size_t)node * WDIM + f] = fmaxf(o, 0.f);
            }
        }
    }
}

// ---------------- host ----------------
static inline size_t align256(size_t x) { return (x + 255) & ~(size_t)255; }

extern "C" void kernel_launch(void* const* d_in, const int* in_sizes, int n_in,
                              void* d_out, int out_size, void* d_ws, size_t ws_size,
                              hipStream_t stream) {
    const int*   x     = (const int*)d_in[0];
    const int*   ei    = (const int*)d_in[1];
    const float* emb   = (const float*)d_in[2];
    const float* Wl0   = (const float*)d_in[3];
    const float* bl0   = (const float*)d_in[4];
    const float* Wr0   = (const float*)d_in[5];
    const float* br0   = (const float*)d_in[6];
    const float* att0  = (const float*)d_in[7];
    const float* bias0 = (const float*)d_in[8];
    const float* Wl    = (const float*)d_in[9];
    const float* bl    = (const float*)d_in[10];
    const float* Wr    = (const float*)d_in[11];
    const float* br    = (const float*)d_in[12];
    const float* att   = (const float*)d_in[13];
    const float* bias  = (const float*)d_in[14];

    char* ws = (char*)d_ws;
    size_t off = 0;
    float* h      = (float*)(ws + off); off = align256(off + (size_t)NODES * WDIM * 4);
    float* xlp    = (float*)(ws + off); off = align256(off + (size_t)NODES * SLOTS * 4);
    float* xrp    = (float*)(ws + off); off = align256(off + (size_t)NODES * SLOTS * 4);
    int* offsets  = (int*)(ws + off);   off = align256(off + (size_t)(NODES + 1) * 4);
    int* csr_src  = (int*)(ws + off);   off = align256(off + (size_t)ETOT * 4);
    bf16x8* bfrag = (bf16x8*)(ws + off); off = align256(off + (size_t)10 * 40 * 2 * 64 * 16);
    // counts/cursor alias xlp: only used during CSR build, before gemm writes xlp
    int* counts   = (int*)xlp;
    int* cursor   = (int*)xlp + NODES;

    float* out = (float*)d_out;

    // CSR build (edges invariant across layers)
    hipMemsetAsync(counts, 0, (size_t)NODES * 4, stream);
    hipMemsetAsync(cursor, 0, (size_t)NODES * 4, stream);
    count_edges<<<(ETOT + 255) / 256, 256, 0, stream>>>(ei, counts);
    scan_kernel<<<1, 1024, 0, stream>>>(counts, offsets, NODES);
    scatter_edges<<<(ETOT + 255) / 256, 256, 0, stream>>>(ei, offsets, cursor, csr_src);

    // h0 = emb[x]
    gather_emb<<<(NODES * D0 + 255) / 256, 256, 0, stream>>>(x, emb, h, NODES, D0);

    int agg_blocks = (NODES + 3) / 4;

    // layer 0 (K = 100, ksteps = 4)
    {
        int ks = 4;
        int bf_total = ks * 40 * 64;
        make_bfrag<<<(bf_total + 255) / 256, 256, 0, stream>>>(Wl0, Wr0, bfrag, D0, ks);
        gemm_mfma<<<1200, 256, 0, stream>>>(h, bfrag, bl0, br0, xlp, xrp, NODES, D0, ks);
        gat_edge_agg<<<agg_blocks, 256, 0, stream>>>(xlp, xrp, offsets, csr_src, att0, bias0, h);
    }

    // layers 1..4 (K = 300, ksteps = 10)
    for (int i = 0; i < 4; i++) {
        const float* Wli = Wl + (size_t)i * WDIM * WDIM;
        const float* Wri = Wr + (size_t)i * WDIM * WDIM;
        float* dst = (i == 3) ? out : h;
        int ks = 10;
        int bf_total = ks * 40 * 64;
        make_bfrag<<<(bf_total + 255) / 256, 256, 0, stream>>>(Wli, Wri, bfrag, WDIM, ks);
        gemm_mfma<<<1200, 256, 0, stream>>>(h, bfrag, bl + i * WDIM, br + i * WDIM,
                                            xlp, xrp, NODES, WDIM, ks);
        gat_edge_agg<<<agg_blocks, 256, 0, stream>>>(xlp, xrp, offsets, csr_src,
                                                     att + (size_t)i * WDIM,
                                                     bias + (size_t)i * WDIM, dst);
    }
}

// Round 6
// 948.763 us; speedup vs baseline: 2.1554x; 2.1554x over previous
//
#include <hip/hip_runtime.h>

#define NODES   30000
#define E0N     480000
#define ETOT    510000   // E0N + NODES self loops
#define D0      100
#define WDIM    300      // H*F = 3*100
#define NW      600      // dual output width
#define NEG     0.2f

typedef __bf16 bf16x8 __attribute__((ext_vector_type(8)));
typedef float  f32x4  __attribute__((ext_vector_type(4)));

// ---------------- embedding gather: h[i,k] = emb[x[i],k] ----------------
__global__ void gather_emb(const int* __restrict__ x, const float* __restrict__ emb,
                           float* __restrict__ h, int n, int d) {
    int t = blockIdx.x * 256 + threadIdx.x;
    if (t >= n * d) return;
    int i = t / d, k = t - i * d;
    h[t] = emb[x[i] * d + k];
}

// ---------------- CSR build ----------------
__global__ void count_edges(const int* __restrict__ ei, int* __restrict__ counts) {
    int e = blockIdx.x * 256 + threadIdx.x;
    if (e >= ETOT) return;
    int d = (e < E0N) ? ei[E0N + e] : (e - E0N);
    atomicAdd(&counts[d], 1);
}

__global__ __launch_bounds__(1024) void scan_kernel(const int* __restrict__ counts,
                                                    int* __restrict__ offsets, int n) {
    __shared__ int lds[1024];
    const int CH = 32;
    int t = threadIdx.x;
    int base = t * CH;
    int loc[CH];
    int sum = 0;
    #pragma unroll
    for (int i = 0; i < CH; i++) {
        int v = (base + i < n) ? counts[base + i] : 0;
        loc[i] = sum;
        sum += v;
    }
    lds[t] = sum;
    __syncthreads();
    for (int off = 1; off < 1024; off <<= 1) {
        int v = (t >= off) ? lds[t - off] : 0;
        __syncthreads();
        lds[t] += v;
        __syncthreads();
    }
    int ex = (t == 0) ? 0 : lds[t - 1];
    #pragma unroll
    for (int i = 0; i < CH; i++) {
        int idx = base + i;
        if (idx < n) offsets[idx] = ex + loc[i];
    }
    if (t == 0) offsets[n] = lds[1023];
}

__global__ void scatter_edges(const int* __restrict__ ei, const int* __restrict__ offsets,
                              int* __restrict__ cursor, int* __restrict__ csr_src) {
    int e = blockIdx.x * 256 + threadIdx.x;
    if (e >= ETOT) return;
    int s, d;
    if (e < E0N) { s = ei[e]; d = ei[E0N + e]; }
    else         { s = e - E0N; d = s; }
    int pos = offsets[d] + atomicAdd(&cursor[d], 1);
    csr_src[pos] = s;
}

// ---------------- B fragment pre-split (hi/lo bf16, MFMA-fragment-linear) ----
__global__ void make_bfrag(const float* __restrict__ Bl, const float* __restrict__ Br,
                           bf16x8* __restrict__ out, int K, int ksteps) {
    int t = blockIdx.x * 256 + threadIdx.x;
    int total = ksteps * 40 * 64;
    if (t >= total) return;
    int lane = t & 63;
    int n16  = (t >> 6) % 40;
    int s    = t / (64 * 40);
    int c = n16 * 16 + (lane & 15);
    union { bf16x8 v; __bf16 e[8]; } hi, lo;
    #pragma unroll
    for (int j = 0; j < 8; j++) {
        int k = s * 32 + ((lane >> 4) * 8) + j;
        float x = 0.f;
        if (k < K && c < NW)
            x = (c < WDIM) ? Bl[(size_t)k * WDIM + c] : Br[(size_t)k * WDIM + c - WDIM];
        __bf16 h = (__bf16)x;
        hi.e[j] = h;
        lo.e[j] = (__bf16)(x - (float)h);
    }
    size_t base = ((size_t)(s * 40 + n16) * 2) * 64 + lane;
    out[base]      = hi.v;
    out[base + 64] = lo.v;
}

// ---------------- MFMA dual GEMM: [Cl|Cr] = A @ [Bl|Br] + [bl|br] ----------
__global__ __launch_bounds__(256) void gemm_mfma(
    const float* __restrict__ A, const bf16x8* __restrict__ Bfrag,
    const float* __restrict__ bl, const float* __restrict__ br,
    float* __restrict__ Cl, float* __restrict__ Cr,
    int M, int K, int ksteps) {

    __shared__ bf16x8 Alds[8][2][64];   // [m16][part][slot]
    __shared__ bf16x8 Blds[8][2][64];   // [n16][part][slot]

    int id = blockIdx.x;
    int mb = (id & 7) + 8 * (id / 40);
    int cb = (id >> 3) % 5;
    if (mb >= 235) return;

    int tid  = threadIdx.x;
    int lane = tid & 63;
    int wid  = tid >> 6;
    int wm = wid >> 1, wn = wid & 1;
    int row0 = mb * 128;

    f32x4 acc[4][4] = {};

    for (int s = 0; s < ksteps; s++) {
        int kt = s * 32;
        #pragma unroll
        for (int u0 = 0; u0 < 2; u0++) {
            int u = u0 * 256 + tid;
            int m16  = u >> 6;
            int slot = u & 63;
            int kh = slot >> 4, rl = slot & 15;
            int gr = row0 + m16 * 16 + rl;
            int gc = kt + kh * 8;
            float4 v0 = make_float4(0.f,0.f,0.f,0.f), v1 = v0;
            if (gr < M) {
                const float* ap = A + (size_t)gr * K + gc;
                if (gc + 4 <= K) v0 = *(const float4*)ap;
                if (gc + 8 <= K) v1 = *(const float4*)(ap + 4);
            }
            union { bf16x8 v; __bf16 e[8]; } hi, lo;
            const float* xs0 = (const float*)&v0;
            const float* xs1 = (const float*)&v1;
            #pragma unroll
            for (int j = 0; j < 8; j++) {
                float x = (j < 4) ? xs0[j] : xs1[j - 4];
                __bf16 h = (__bf16)x;
                hi.e[j] = h;
                lo.e[j] = (__bf16)(x - (float)h);
            }
            Alds[m16][0][slot] = hi.v;
            Alds[m16][1][slot] = lo.v;
        }
        {
            const float4* bsrc = (const float4*)(Bfrag + ((size_t)(s * 40 + cb * 8) * 2) * 64);
            float4* bdst = (float4*)&Blds[0][0][0];
            #pragma unroll
            for (int c = 0; c < 4; c++)
                bdst[c * 256 + tid] = bsrc[c * 256 + tid];
        }
        __syncthreads();

        bf16x8 af[4][2], bfr[4][2];
        #pragma unroll
        for (int m = 0; m < 4; m++) {
            af[m][0] = Alds[wm * 4 + m][0][lane];
            af[m][1] = Alds[wm * 4 + m][1][lane];
        }
        #pragma unroll
        for (int n = 0; n < 4; n++) {
            bfr[n][0] = Blds[wn * 4 + n][0][lane];
            bfr[n][1] = Blds[wn * 4 + n][1][lane];
        }
        #pragma unroll
        for (int m = 0; m < 4; m++)
            #pragma unroll
            for (int n = 0; n < 4; n++) {
                acc[m][n] = __builtin_amdgcn_mfma_f32_16x16x32_bf16(af[m][1], bfr[n][1], acc[m][n], 0, 0, 0);
                acc[m][n] = __builtin_amdgcn_mfma_f32_16x16x32_bf16(af[m][1], bfr[n][0], acc[m][n], 0, 0, 0);
                acc[m][n] = __builtin_amdgcn_mfma_f32_16x16x32_bf16(af[m][0], bfr[n][1], acc[m][n], 0, 0, 0);
                acc[m][n] = __builtin_amdgcn_mfma_f32_16x16x32_bf16(af[m][0], bfr[n][0], acc[m][n], 0, 0, 0);
            }
        __syncthreads();
    }

    // epilogue: D row=(lane>>4)*4+reg, col=lane&15; bias; flat store
    int r0 = row0 + wm * 64;
    int c0 = cb * 128 + wn * 64;
    #pragma unroll
    for (int m = 0; m < 4; m++)
        #pragma unroll
        for (int n = 0; n < 4; n++) {
            #pragma unroll
            for (int reg = 0; reg < 4; reg++) {
                int gr = r0 + m * 16 + (lane >> 4) * 4 + reg;
                int gc = c0 + n * 16 + (lane & 15);
                if (gr < M && gc < NW) {
                    bool left = gc < WDIM;
                    int cc = left ? gc : gc - WDIM;
                    float v = acc[m][n][reg] + (left ? bl[cc] : br[cc]);
                    (left ? Cl : Cr)[(size_t)gr * WDIM + cc] = v;
                }
            }
        }
}

// ---------------- fused GAT: wave-per-node, 2-edge ILP, packed reduce, defer-rescale ----
__global__ __launch_bounds__(256) void gat_edge_agg(
    const float* __restrict__ xl, const float* __restrict__ xr,
    const int* __restrict__ offsets, const int* __restrict__ csr_src,
    const float* __restrict__ att, const float* __restrict__ bias,
    float* __restrict__ hout) {
    int node = (blockIdx.x * 256 + threadIdx.x) >> 6;
    int lane = threadIdx.x & 63;
    if (node >= NODES) return;

    // resident: att (0 at f>=300) and xr row (unguarded loads; slack exists, aw=0 kills pads)
    float aw[5], xrv[5];
    #pragma unroll
    for (int j = 0; j < 5; j++) {
        int f = lane + 64 * j;
        aw[j]  = (f < WDIM) ? att[f] : 0.f;
        xrv[j] = xr[(size_t)node * WDIM + ((f < WDIM) ? f : 0)];
    }

    float m0 = -1e38f, m1 = -1e38f, m2 = -1e38f;
    float s0 = 0.f, s1 = 0.f, s2 = 0.f;
    float acc[5] = {};

    int beg = offsets[node], end = offsets[node + 1];
    for (int i = beg; i < end; i += 2) {
        bool act_b = (i + 1) < end;
        int sa = csr_src[i];
        int sb = csr_src[act_b ? i + 1 : i];
        const float* ra = xl + (size_t)sa * WDIM;
        const float* rb = xl + (size_t)sb * WDIM;
        float va[5], vb[5];
        #pragma unroll
        for (int j = 0; j < 5; j++) {   // unguarded: 19-float slack into next ws buffer
            va[j] = ra[lane + 64 * j];
            vb[j] = rb[lane + 64 * j];
        }
        float pa0 = 0.f, pa1 = 0.f, pa2 = 0.f;
        float pb0 = 0.f, pb1 = 0.f, pb2 = 0.f;
        #pragma unroll
        for (int j = 0; j < 5; j++) {
            int f = lane + 64 * j;
            float ta = va[j] + xrv[j]; ta = fmaxf(ta, NEG * ta);
            float tb = vb[j] + xrv[j]; tb = fmaxf(tb, NEG * tb);
            float qa = ta * aw[j], qb = tb * aw[j];
            if (j == 0)      { pa0 += qa; pb0 += qb; }
            else if (j == 2) { pa1 += qa; pb1 += qb; }
            else if (j == 4) { pa2 += qa; pb2 += qb; }
            else if (j == 1) {
                if (f < 100) { pa0 += qa; pb0 += qb; } else { pa1 += qa; pb1 += qb; }
            } else { // j == 3
                if (f < 200) { pa1 += qa; pb1 += qb; } else { pa2 += qa; pb2 += qb; }
            }
        }
        // packed reduce: stages 1,2 on all 6; pack by lane&3; stages 4..32 on 2; broadcast
        pa0 += __shfl_xor(pa0, 1, 64); pa1 += __shfl_xor(pa1, 1, 64); pa2 += __shfl_xor(pa2, 1, 64);
        pb0 += __shfl_xor(pb0, 1, 64); pb1 += __shfl_xor(pb1, 1, 64); pb2 += __shfl_xor(pb2, 1, 64);
        pa0 += __shfl_xor(pa0, 2, 64); pa1 += __shfl_xor(pa1, 2, 64); pa2 += __shfl_xor(pa2, 2, 64);
        pb0 += __shfl_xor(pb0, 2, 64); pb1 += __shfl_xor(pb1, 2, 64); pb2 += __shfl_xor(pb2, 2, 64);
        int r = lane & 3;
        float qa = (r == 1) ? pa1 : ((r == 2) ? pa2 : pa0);
        float qb = (r == 1) ? pb1 : ((r == 2) ? pb2 : pb0);
        qa += __shfl_xor(qa, 4, 64);  qb += __shfl_xor(qb, 4, 64);
        qa += __shfl_xor(qa, 8, 64);  qb += __shfl_xor(qb, 8, 64);
        qa += __shfl_xor(qa, 16, 64); qb += __shfl_xor(qb, 16, 64);
        qa += __shfl_xor(qa, 32, 64); qb += __shfl_xor(qb, 32, 64);
        pa0 = __shfl(qa, 0, 64); pa1 = __shfl(qa, 1, 64); pa2 = __shfl(qa, 2, 64);
        pb0 = __shfl(qb, 0, 64); pb1 = __shfl(qb, 1, 64); pb2 = __shfl(qb, 2, 64);
        if (!act_b) { pb0 = -3e38f; pb1 = -3e38f; pb2 = -3e38f; }

        // defer-rescale online softmax (THR = 8)
        float hi0 = fmaxf(pa0, pb0), hi1 = fmaxf(pa1, pb1), hi2 = fmaxf(pa2, pb2);
        if (hi0 > m0 + 8.f || hi1 > m1 + 8.f || hi2 > m2 + 8.f) {
            float nm0 = fmaxf(m0, hi0), nm1 = fmaxf(m1, hi1), nm2 = fmaxf(m2, hi2);
            float e0 = __expf(m0 - nm0), e1 = __expf(m1 - nm1), e2 = __expf(m2 - nm2);
            s0 *= e0; s1 *= e1; s2 *= e2;
            #pragma unroll
            for (int j = 0; j < 5; j++) {
                int f = lane + 64 * j;
                float e = (j == 0) ? e0 : (j == 2) ? e1 : (j == 4) ? e2 :
                          (j == 1) ? ((f < 100) ? e0 : e1) : ((f < 200) ? e1 : e2);
                acc[j] *= e;
            }
            m0 = nm0; m1 = nm1; m2 = nm2;
        }
        float ca0 = __expf(pa0 - m0), ca1 = __expf(pa1 - m1), ca2 = __expf(pa2 - m2);
        float cb0 = __expf(pb0 - m0), cb1 = __expf(pb1 - m1), cb2 = __expf(pb2 - m2);
        s0 += ca0 + cb0; s1 += ca1 + cb1; s2 += ca2 + cb2;
        #pragma unroll
        for (int j = 0; j < 5; j++) {
            int f = lane + 64 * j;
            float ca = (j == 0) ? ca0 : (j == 2) ? ca1 : (j == 4) ? ca2 :
                       (j == 1) ? ((f < 100) ? ca0 : ca1) : ((f < 200) ? ca1 : ca2);
            float cb = (j == 0) ? cb0 : (j == 2) ? cb1 : (j == 4) ? cb2 :
                       (j == 1) ? ((f < 100) ? cb0 : cb1) : ((f < 200) ? cb1 : cb2);
            acc[j] = fmaf(ca, va[j], acc[j]);
            acc[j] = fmaf(cb, vb[j], acc[j]);
        }
    }

    float i0 = 1.f / s0, i1 = 1.f / s1, i2 = 1.f / s2;
    #pragma unroll
    for (int j = 0; j < 5; j++) {
        int f = lane + 64 * j;
        if (f < WDIM) {
            float is = (j == 0) ? i0 : (j == 2) ? i1 : (j == 4) ? i2 :
                       (j == 1) ? ((f < 100) ? i0 : i1) : ((f < 200) ? i1 : i2);
            float o = acc[j] * is + bias[f];
            hout[(size_t)node * WDIM + f] = fmaxf(o, 0.f);
        }
    }
}

// ---------------- host ----------------
static inline size_t align256(size_t x) { return (x + 255) & ~(size_t)255; }

extern "C" void kernel_launch(void* const* d_in, const int* in_sizes, int n_in,
                              void* d_out, int out_size, void* d_ws, size_t ws_size,
                              hipStream_t stream) {
    const int*   x     = (const int*)d_in[0];
    const int*   ei    = (const int*)d_in[1];
    const float* emb   = (const float*)d_in[2];
    const float* Wl0   = (const float*)d_in[3];
    const float* bl0   = (const float*)d_in[4];
    const float* Wr0   = (const float*)d_in[5];
    const float* br0   = (const float*)d_in[6];
    const float* att0  = (const float*)d_in[7];
    const float* bias0 = (const float*)d_in[8];
    const float* Wl    = (const float*)d_in[9];
    const float* bl    = (const float*)d_in[10];
    const float* Wr    = (const float*)d_in[11];
    const float* br    = (const float*)d_in[12];
    const float* att   = (const float*)d_in[13];
    const float* bias  = (const float*)d_in[14];

    char* ws = (char*)d_ws;
    size_t off = 0;
    float* h      = (float*)(ws + off); off = align256(off + (size_t)NODES * WDIM * 4);
    float* xlb    = (float*)(ws + off); off = align256(off + (size_t)NODES * WDIM * 4);
    float* xrb    = (float*)(ws + off); off = align256(off + (size_t)NODES * WDIM * 4);
    int* counts   = (int*)(ws + off);   off = align256(off + (size_t)NODES * 4);
    int* cursor   = (int*)(ws + off);   off = align256(off + (size_t)NODES * 4);
    int* offsets  = (int*)(ws + off);   off = align256(off + (size_t)(NODES + 1) * 4);
    int* csr_src  = (int*)(ws + off);   off = align256(off + (size_t)ETOT * 4);
    bf16x8* bfrag = (bf16x8*)(ws + off); off = align256(off + (size_t)10 * 40 * 2 * 64 * 16);

    float* out = (float*)d_out;

    // CSR build (edges invariant across layers)
    hipMemsetAsync(counts, 0, (size_t)NODES * 4, stream);
    hipMemsetAsync(cursor, 0, (size_t)NODES * 4, stream);
    count_edges<<<(ETOT + 255) / 256, 256, 0, stream>>>(ei, counts);
    scan_kernel<<<1, 1024, 0, stream>>>(counts, offsets, NODES);
    scatter_edges<<<(ETOT + 255) / 256, 256, 0, stream>>>(ei, offsets, cursor, csr_src);

    // h0 = emb[x]
    gather_emb<<<(NODES * D0 + 255) / 256, 256, 0, stream>>>(x, emb, h, NODES, D0);

    int agg_blocks = (NODES + 3) / 4;

    // layer 0 (K = 100, ksteps = 4)
    {
        int ks = 4;
        int bf_total = ks * 40 * 64;
        make_bfrag<<<(bf_total + 255) / 256, 256, 0, stream>>>(Wl0, Wr0, bfrag, D0, ks);
        gemm_mfma<<<1200, 256, 0, stream>>>(h, bfrag, bl0, br0, xlb, xrb, NODES, D0, ks);
        gat_edge_agg<<<agg_blocks, 256, 0, stream>>>(xlb, xrb, offsets, csr_src, att0, bias0, h);
    }

    // layers 1..4 (K = 300, ksteps = 10)
    for (int i = 0; i < 4; i++) {
        const float* Wli = Wl + (size_t)i * WDIM * WDIM;
        const float* Wri = Wr + (size_t)i * WDIM * WDIM;
        float* dst = (i == 3) ? out : h;
        int ks = 10;
        int bf_total = ks * 40 * 64;
        make_bfrag<<<(bf_total + 255) / 256, 256, 0, stream>>>(Wli, Wri, bfrag, WDIM, ks);
        gemm_mfma<<<1200, 256, 0, stream>>>(h, bfrag, bl + i * WDIM, br + i * WDIM,
                                            xlb, xrb, NODES, WDIM, ks);
        gat_edge_agg<<<agg_blocks, 256, 0, stream>>>(xlb, xrb, offsets, csr_src,
                                                     att + (size_t)i * WDIM,
                                                     bias + (size_t)i * WDIM, dst);
    }
}

// Round 7
// 917.550 us; speedup vs baseline: 2.2287x; 1.0340x over previous
//
#include <hip/hip_runtime.h>

#define NODES   30000
#define E0N     480000
#define ETOT    510000   // E0N + NODES self loops
#define D0      100
#define WDIM    300      // H*F = 3*100
#define NW      600      // dual output width
#define NEG     0.2f

typedef __bf16 bf16x8 __attribute__((ext_vector_type(8)));
typedef float  f32x4  __attribute__((ext_vector_type(4)));

// ---------------- CSR build ----------------
__global__ void count_edges(const int* __restrict__ ei, int* __restrict__ counts) {
    int e = blockIdx.x * 256 + threadIdx.x;
    if (e >= ETOT) return;
    int d = (e < E0N) ? ei[E0N + e] : (e - E0N);
    atomicAdd(&counts[d], 1);
}

__global__ __launch_bounds__(1024) void scan_kernel(const int* __restrict__ counts,
                                                    int* __restrict__ offsets, int n) {
    __shared__ int lds[1024];
    const int CH = 32;
    int t = threadIdx.x;
    int base = t * CH;
    int loc[CH];
    int sum = 0;
    #pragma unroll
    for (int i = 0; i < CH; i++) {
        int v = (base + i < n) ? counts[base + i] : 0;
        loc[i] = sum;
        sum += v;
    }
    lds[t] = sum;
    __syncthreads();
    for (int off = 1; off < 1024; off <<= 1) {
        int v = (t >= off) ? lds[t - off] : 0;
        __syncthreads();
        lds[t] += v;
        __syncthreads();
    }
    int ex = (t == 0) ? 0 : lds[t - 1];
    #pragma unroll
    for (int i = 0; i < CH; i++) {
        int idx = base + i;
        if (idx < n) offsets[idx] = ex + loc[i];
    }
    if (t == 0) offsets[n] = lds[1023];
}

__global__ void scatter_edges(const int* __restrict__ ei, const int* __restrict__ offsets,
                              int* __restrict__ cursor, int* __restrict__ csr_src) {
    int e = blockIdx.x * 256 + threadIdx.x;
    if (e >= ETOT) return;
    int s, d;
    if (e < E0N) { s = ei[e]; d = ei[E0N + e]; }
    else         { s = e - E0N; d = s; }
    int pos = offsets[d] + atomicAdd(&cursor[d], 1);
    csr_src[pos] = s;
}

// ---------------- B fragment pre-split (hi/lo bf16, MFMA-fragment-linear) ----
__global__ void make_bfrag(const float* __restrict__ Bl, const float* __restrict__ Br,
                           bf16x8* __restrict__ out, int K, int ksteps) {
    int t = blockIdx.x * 256 + threadIdx.x;
    int total = ksteps * 40 * 64;
    if (t >= total) return;
    int lane = t & 63;
    int n16  = (t >> 6) % 40;
    int s    = t / (64 * 40);
    int c = n16 * 16 + (lane & 15);
    union { bf16x8 v; __bf16 e[8]; } hi, lo;
    #pragma unroll
    for (int j = 0; j < 8; j++) {
        int k = s * 32 + ((lane >> 4) * 8) + j;
        float x = 0.f;
        if (k < K && c < NW)
            x = (c < WDIM) ? Bl[(size_t)k * WDIM + c] : Br[(size_t)k * WDIM + c - WDIM];
        __bf16 h = (__bf16)x;
        hi.e[j] = h;
        lo.e[j] = (__bf16)(x - (float)h);
    }
    size_t base = ((size_t)(s * 40 + n16) * 2) * 64 + lane;
    out[base]      = hi.v;
    out[base + 64] = lo.v;
}

// ---------------- MFMA dual GEMM: [Cl|Cr] = A @ [Bl|Br] + [bl|br] ----------
// split-bf16 hi/lo, 3 cross-product MFMAs (ll dropped), f32 accumulate.
// use_map: row indirection A-row = xmap[gr] (layer-0 embedding fold-in).
__global__ __launch_bounds__(256) void gemm_mfma(
    const float* __restrict__ A, const int* __restrict__ xmap, int use_map,
    const bf16x8* __restrict__ Bfrag,
    const float* __restrict__ bl, const float* __restrict__ br,
    float* __restrict__ Cl, float* __restrict__ Cr,
    int M, int K, int ksteps) {

    __shared__ bf16x8 Alds[8][2][64];   // [m16][part][slot]
    __shared__ bf16x8 Blds[8][2][64];   // [n16][part][slot]

    int id = blockIdx.x;
    int mb = (id & 7) + 8 * (id / 40);
    int cb = (id >> 3) % 5;
    if (mb >= 235) return;

    int tid  = threadIdx.x;
    int lane = tid & 63;
    int wid  = tid >> 6;
    int wm = wid >> 1, wn = wid & 1;
    int row0 = mb * 128;

    f32x4 acc[4][4] = {};

    for (int s = 0; s < ksteps; s++) {
        int kt = s * 32;
        #pragma unroll
        for (int u0 = 0; u0 < 2; u0++) {
            int u = u0 * 256 + tid;
            int m16  = u >> 6;
            int slot = u & 63;
            int kh = slot >> 4, rl = slot & 15;
            int gr = row0 + m16 * 16 + rl;
            int gc = kt + kh * 8;
            float4 v0 = make_float4(0.f,0.f,0.f,0.f), v1 = v0;
            if (gr < M) {
                int ar = use_map ? xmap[gr] : gr;
                const float* ap = A + (size_t)ar * K + gc;
                if (gc + 4 <= K) v0 = *(const float4*)ap;
                if (gc + 8 <= K) v1 = *(const float4*)(ap + 4);
            }
            union { bf16x8 v; __bf16 e[8]; } hi, lo;
            const float* xs0 = (const float*)&v0;
            const float* xs1 = (const float*)&v1;
            #pragma unroll
            for (int j = 0; j < 8; j++) {
                float x = (j < 4) ? xs0[j] : xs1[j - 4];
                __bf16 h = (__bf16)x;
                hi.e[j] = h;
                lo.e[j] = (__bf16)(x - (float)h);
            }
            Alds[m16][0][slot] = hi.v;
            Alds[m16][1][slot] = lo.v;
        }
        {
            const float4* bsrc = (const float4*)(Bfrag + ((size_t)(s * 40 + cb * 8) * 2) * 64);
            float4* bdst = (float4*)&Blds[0][0][0];
            #pragma unroll
            for (int c = 0; c < 4; c++)
                bdst[c * 256 + tid] = bsrc[c * 256 + tid];
        }
        __syncthreads();

        bf16x8 af[4][2], bfr[4][2];
        #pragma unroll
        for (int m = 0; m < 4; m++) {
            af[m][0] = Alds[wm * 4 + m][0][lane];
            af[m][1] = Alds[wm * 4 + m][1][lane];
        }
        #pragma unroll
        for (int n = 0; n < 4; n++) {
            bfr[n][0] = Blds[wn * 4 + n][0][lane];
            bfr[n][1] = Blds[wn * 4 + n][1][lane];
        }
        #pragma unroll
        for (int m = 0; m < 4; m++)
            #pragma unroll
            for (int n = 0; n < 4; n++) {
                acc[m][n] = __builtin_amdgcn_mfma_f32_16x16x32_bf16(af[m][1], bfr[n][0], acc[m][n], 0, 0, 0);
                acc[m][n] = __builtin_amdgcn_mfma_f32_16x16x32_bf16(af[m][0], bfr[n][1], acc[m][n], 0, 0, 0);
                acc[m][n] = __builtin_amdgcn_mfma_f32_16x16x32_bf16(af[m][0], bfr[n][0], acc[m][n], 0, 0, 0);
            }
        __syncthreads();
    }

    // epilogue: D row=(lane>>4)*4+reg, col=lane&15; bias; flat store
    int r0 = row0 + wm * 64;
    int c0 = cb * 128 + wn * 64;
    #pragma unroll
    for (int m = 0; m < 4; m++)
        #pragma unroll
        for (int n = 0; n < 4; n++) {
            #pragma unroll
            for (int reg = 0; reg < 4; reg++) {
                int gr = r0 + m * 16 + (lane >> 4) * 4 + reg;
                int gc = c0 + n * 16 + (lane & 15);
                if (gr < M && gc < NW) {
                    bool left = gc < WDIM;
                    int cc = left ? gc : gc - WDIM;
                    float v = acc[m][n][reg] + (left ? bl[cc] : br[cc]);
                    (left ? Cl : Cr)[(size_t)gr * WDIM + cc] = v;
                }
            }
        }
}

// ---------------- fused GAT: wave-per-node, 2-edge ILP, residue-packed softmax ----
// Softmax state (m,s) lives packed by lane residue r=lane&3: r=0:head0 r=1:head1 r=2:head2.
__global__ __launch_bounds__(256) void gat_edge_agg(
    const float* __restrict__ xl, const float* __restrict__ xr,
    const int* __restrict__ offsets, const int* __restrict__ csr_src,
    const float* __restrict__ att, const float* __restrict__ bias,
    float* __restrict__ hout) {
    int node = (blockIdx.x * 256 + threadIdx.x) >> 6;
    int lane = threadIdx.x & 63;
    if (node >= NODES) return;
    int r = lane & 3;

    float aw[5], xrv[5];
    #pragma unroll
    for (int j = 0; j < 5; j++) {
        int f = lane + 64 * j;
        aw[j]  = (f < WDIM) ? att[f] : 0.f;
        xrv[j] = xr[(size_t)node * WDIM + ((f < WDIM) ? f : 0)];
    }

    float mq = -1e38f, sq = 0.f;   // packed per-residue (r=3 duplicates head0)
    float acc[5] = {};

    int beg = offsets[node], end = offsets[node + 1];
    for (int i = beg; i < end; i += 2) {
        bool act_b = (i + 1) < end;
        int sa = csr_src[i];
        int sb = csr_src[act_b ? i + 1 : i];
        const float* ra = xl + (size_t)sa * WDIM;
        const float* rb = xl + (size_t)sb * WDIM;
        float va[5], vb[5];
        #pragma unroll
        for (int j = 0; j < 5; j++) {   // unguarded: 19-float slack into next ws buffer
            va[j] = ra[lane + 64 * j];
            vb[j] = rb[lane + 64 * j];
        }
        float pa0 = 0.f, pa1 = 0.f, pa2 = 0.f;
        float pb0 = 0.f, pb1 = 0.f, pb2 = 0.f;
        #pragma unroll
        for (int j = 0; j < 5; j++) {
            int f = lane + 64 * j;
            float ta = va[j] + xrv[j]; ta = fmaxf(ta, NEG * ta);
            float tb = vb[j] + xrv[j]; tb = fmaxf(tb, NEG * tb);
            float qa = ta * aw[j], qb = tb * aw[j];
            if (j == 0)      { pa0 += qa; pb0 += qb; }
            else if (j == 2) { pa1 += qa; pb1 += qb; }
            else if (j == 4) { pa2 += qa; pb2 += qb; }
            else if (j == 1) {
                if (f < 100) { pa0 += qa; pb0 += qb; } else { pa1 += qa; pb1 += qb; }
            } else { // j == 3
                if (f < 200) { pa1 += qa; pb1 += qb; } else { pa2 += qa; pb2 += qb; }
            }
        }
        // stages 1,2 on all 6 partials; pack by residue; stages 4..32 on 2
        pa0 += __shfl_xor(pa0, 1, 64); pa1 += __shfl_xor(pa1, 1, 64); pa2 += __shfl_xor(pa2, 1, 64);
        pb0 += __shfl_xor(pb0, 1, 64); pb1 += __shfl_xor(pb1, 1, 64); pb2 += __shfl_xor(pb2, 1, 64);
        pa0 += __shfl_xor(pa0, 2, 64); pa1 += __shfl_xor(pa1, 2, 64); pa2 += __shfl_xor(pa2, 2, 64);
        pb0 += __shfl_xor(pb0, 2, 64); pb1 += __shfl_xor(pb1, 2, 64); pb2 += __shfl_xor(pb2, 2, 64);
        float qa = (r == 1) ? pa1 : ((r == 2) ? pa2 : pa0);
        float qb = (r == 1) ? pb1 : ((r == 2) ? pb2 : pb0);
        qa += __shfl_xor(qa, 4, 64);  qb += __shfl_xor(qb, 4, 64);
        qa += __shfl_xor(qa, 8, 64);  qb += __shfl_xor(qb, 8, 64);
        qa += __shfl_xor(qa, 16, 64); qb += __shfl_xor(qb, 16, 64);
        qa += __shfl_xor(qa, 32, 64); qb += __shfl_xor(qb, 32, 64);
        if (!act_b) qb = -3e38f;

        // defer-rescale (THR=8), packed state
        float hiq = fmaxf(qa, qb);
        if (__any(hiq > mq + 8.f)) {
            float nmq = fmaxf(mq, hiq);
            float eq = __expf(mq - nmq);
            sq *= eq;
            float e0 = __shfl(eq, 0, 64), e1 = __shfl(eq, 1, 64), e2 = __shfl(eq, 2, 64);
            #pragma unroll
            for (int j = 0; j < 5; j++) {
                int f = lane + 64 * j;
                float e = (j == 0) ? e0 : (j == 2) ? e1 : (j == 4) ? e2 :
                          (j == 1) ? ((f < 100) ? e0 : e1) : ((f < 200) ? e1 : e2);
                acc[j] *= e;
            }
            mq = nmq;
        }
        float cqa = __expf(qa - mq), cqb = __expf(qb - mq);
        sq += cqa + cqb;
        float ca0 = __shfl(cqa, 0, 64), ca1 = __shfl(cqa, 1, 64), ca2 = __shfl(cqa, 2, 64);
        float cb0 = __shfl(cqb, 0, 64), cb1 = __shfl(cqb, 1, 64), cb2 = __shfl(cqb, 2, 64);
        #pragma unroll
        for (int j = 0; j < 5; j++) {
            int f = lane + 64 * j;
            float ca = (j == 0) ? ca0 : (j == 2) ? ca1 : (j == 4) ? ca2 :
                       (j == 1) ? ((f < 100) ? ca0 : ca1) : ((f < 200) ? ca1 : ca2);
            float cb = (j == 0) ? cb0 : (j == 2) ? cb1 : (j == 4) ? cb2 :
                       (j == 1) ? ((f < 100) ? cb0 : cb1) : ((f < 200) ? cb1 : cb2);
            acc[j] = fmaf(ca, va[j], acc[j]);
            acc[j] = fmaf(cb, vb[j], acc[j]);
        }
    }

    float iq = 1.f / sq;
    float i0 = __shfl(iq, 0, 64), i1 = __shfl(iq, 1, 64), i2 = __shfl(iq, 2, 64);
    #pragma unroll
    for (int j = 0; j < 5; j++) {
        int f = lane + 64 * j;
        if (f < WDIM) {
            float is = (j == 0) ? i0 : (j == 2) ? i1 : (j == 4) ? i2 :
                       (j == 1) ? ((f < 100) ? i0 : i1) : ((f < 200) ? i1 : i2);
            float o = acc[j] * is + bias[f];
            hout[(size_t)node * WDIM + f] = fmaxf(o, 0.f);
        }
    }
}

// ---------------- host ----------------
static inline size_t align256(size_t x) { return (x + 255) & ~(size_t)255; }

extern "C" void kernel_launch(void* const* d_in, const int* in_sizes, int n_in,
                              void* d_out, int out_size, void* d_ws, size_t ws_size,
                              hipStream_t stream) {
    const int*   x     = (const int*)d_in[0];
    const int*   ei    = (const int*)d_in[1];
    const float* emb   = (const float*)d_in[2];
    const float* Wl0   = (const float*)d_in[3];
    const float* bl0   = (const float*)d_in[4];
    const float* Wr0   = (const float*)d_in[5];
    const float* br0   = (const float*)d_in[6];
    const float* att0  = (const float*)d_in[7];
    const float* bias0 = (const float*)d_in[8];
    const float* Wl    = (const float*)d_in[9];
    const float* bl    = (const float*)d_in[10];
    const float* Wr    = (const float*)d_in[11];
    const float* br    = (const float*)d_in[12];
    const float* att   = (const float*)d_in[13];
    const float* bias  = (const float*)d_in[14];

    char* ws = (char*)d_ws;
    size_t off = 0;
    float* h      = (float*)(ws + off); off = align256(off + (size_t)NODES * WDIM * 4);
    float* xlb    = (float*)(ws + off); off = align256(off + (size_t)NODES * WDIM * 4);
    float* xrb    = (float*)(ws + off); off = align256(off + (size_t)NODES * WDIM * 4);
    int* counts   = (int*)(ws + off);   off = align256(off + (size_t)NODES * 4);
    int* cursor   = (int*)(ws + off);   off = align256(off + (size_t)NODES * 4);
    int* offsets  = (int*)(ws + off);   off = align256(off + (size_t)(NODES + 1) * 4);
    int* csr_src  = (int*)(ws + off);   off = align256(off + (size_t)ETOT * 4);
    bf16x8* bfrag[5];
    bfrag[0] = (bf16x8*)(ws + off); off = align256(off + (size_t)4 * 40 * 2 * 64 * 16);
    for (int i = 1; i < 5; i++) {
        bfrag[i] = (bf16x8*)(ws + off); off = align256(off + (size_t)10 * 40 * 2 * 64 * 16);
    }

    float* out = (float*)d_out;

    // weight fragment pre-splits for all layers up-front
    make_bfrag<<<(4 * 40 * 64 + 255) / 256, 256, 0, stream>>>(Wl0, Wr0, bfrag[0], D0, 4);
    for (int i = 0; i < 4; i++)
        make_bfrag<<<(10 * 40 * 64 + 255) / 256, 256, 0, stream>>>(
            Wl + (size_t)i * WDIM * WDIM, Wr + (size_t)i * WDIM * WDIM, bfrag[i + 1], WDIM, 10);

    // CSR build (edges invariant across layers)
    hipMemsetAsync(counts, 0, (size_t)NODES * 4, stream);
    hipMemsetAsync(cursor, 0, (size_t)NODES * 4, stream);
    count_edges<<<(ETOT + 255) / 256, 256, 0, stream>>>(ei, counts);
    scan_kernel<<<1, 1024, 0, stream>>>(counts, offsets, NODES);
    scatter_edges<<<(ETOT + 255) / 256, 256, 0, stream>>>(ei, offsets, cursor, csr_src);

    int agg_blocks = (NODES + 3) / 4;

    // layer 0 (K = 100, ksteps = 4): A = emb with row indirection via x
    gemm_mfma<<<1200, 256, 0, stream>>>(emb, x, 1, bfrag[0], bl0, br0, xlb, xrb, NODES, D0, 4);
    gat_edge_agg<<<agg_blocks, 256, 0, stream>>>(xlb, xrb, offsets, csr_src, att0, bias0, h);

    // layers 1..4 (K = 300, ksteps = 10)
    for (int i = 0; i < 4; i++) {
        float* dst = (i == 3) ? out : h;
        gemm_mfma<<<1200, 256, 0, stream>>>(h, nullptr, 0, bfrag[i + 1], bl + i * WDIM, br + i * WDIM,
                                            xlb, xrb, NODES, WDIM, 10);
        gat_edge_agg<<<agg_blocks, 256, 0, stream>>>(xlb, xrb, offsets, csr_src,
                                                     att + (size_t)i * WDIM,
                                                     bias + (size_t)i * WDIM, dst);
    }
}